// Round 9
// baseline (114.026 us; speedup 1.0000x reference)
//
#include <hip/hip_runtime.h>
#include <hip/hip_bf16.h>

typedef float f32x4 __attribute__((ext_vector_type(4)));
typedef __bf16 bf16x8 __attribute__((ext_vector_type(8)));

#define EPSF 1e-5f

// ---------------------------------------------------------------- pooling ---
__device__ __forceinline__ float pw(int i) {
    return (1.0f + (i < 64 ? 2.0f : 0.0f) + (i < 32 ? 4.0f : 0.0f)) * (1.0f / 128.0f);
}

__global__ __launch_bounds__(256) void pool_kernel(const float* __restrict__ x,
                                                   float* __restrict__ P) {
    int nc = blockIdx.x;  // n*128 + c
    const f32x4* plane = (const f32x4*)(x + (size_t)nc * 16384);
    __shared__ float rowpart[128][33];
    __shared__ __align__(16) f32x4 colpart[8][32];
    int t = threadIdx.x;
    int wq = t & 31, hg = t >> 5;
    f32x4 cacc = {0.f, 0.f, 0.f, 0.f};
    float u0 = pw(wq * 4), u1 = pw(wq * 4 + 1), u2 = pw(wq * 4 + 2), u3 = pw(wq * 4 + 3);
    #pragma unroll
    for (int j = 0; j < 16; ++j) {
        int r = hg * 16 + j;
        f32x4 v = plane[r * 32 + wq];
        rowpart[r][wq] = v.x * u0 + v.y * u1 + v.z * u2 + v.w * u3;
        cacc += v * pw(r);
    }
    colpart[hg][wq] = cacc;
    __syncthreads();
    float s = 0.f;
    if (t < 128) {
        #pragma unroll
        for (int q = 0; q < 32; ++q) s += rowpart[t][q];
        P[(size_t)nc * 256 + t] = s;
    } else {
        int w = t - 128;
        const float* cp = (const float*)colpart;
        #pragma unroll
        for (int g = 0; g < 8; ++g) s += cp[g * 128 + w];
        P[(size_t)nc * 256 + 128 + w] = s;
    }
}

// ------------------------- attention vectors + fused weight transform -------
// blocks 0..31: attn (n = b>>2, cg = b&3). blocks 32..607: wtrans.
__global__ __launch_bounds__(256) void attn_wtrans_kernel(const float* __restrict__ P,
    const float* __restrict__ w1, const float* __restrict__ b1,
    const float* __restrict__ g1, const float* __restrict__ be1,
    const float* __restrict__ m1, const float* __restrict__ v1,
    const float* __restrict__ wh, const float* __restrict__ bh,
    const float* __restrict__ ww, const float* __restrict__ bw,
    const float* __restrict__ wc, const float* __restrict__ bc,
    const float* __restrict__ g2, const float* __restrict__ be2,
    const float* __restrict__ m2, const float* __restrict__ v2,
    float* __restrict__ A2, __hip_bfloat16* __restrict__ Wt, float* __restrict__ ab) {
    int t = threadIdx.x;
    if (blockIdx.x >= 32) {
        int g = (blockIdx.x - 32) * 256 + t;   // 576*256 == 147456
        int step = g >> 12, rem = g & 4095;
        int o = rem >> 5, m = rem & 31;
        int slotp = m >> 3, j = m & 7;
        int u = slotp ^ ((o >> 1) & 3);
        int kidx = u * 8 + j;
        int khw = step >> 2, c32 = step & 3;
        int c = c32 * 32 + kidx;
        Wt[g] = __float2bfloat16(wc[(o * 128 + c) * 9 + khw]);
        if (g < 128) {
            float s2 = g2[g] * rsqrtf(v2[g] + EPSF);
            ab[g] = s2;
            ab[128 + g] = bc[g] * s2 + be2[g] - m2[g] * s2;
        }
        return;
    }
    int n = blockIdx.x >> 2, cg = blockIdx.x & 3;
    __shared__ float w1s[1024], whs[256], wws[256];
    __shared__ float bhs[32], bws[32];
    __shared__ float s1[8], t1[8], b1s[8];
    for (int i = t; i < 1024; i += 256) w1s[i] = w1[i];
    whs[t] = wh[cg * 256 + t];
    wws[t] = ww[cg * 256 + t];
    if (t < 32) { bhs[t] = bh[cg * 32 + t]; bws[t] = bw[cg * 32 + t]; }
    if (t < 8) {
        float s = g1[t] * rsqrtf(v1[t] + EPSF);
        s1[t] = s; t1[t] = be1[t] - m1[t] * s; b1s[t] = b1[t];
    }
    __syncthreads();
    float y[8];
    #pragma unroll
    for (int m = 0; m < 8; ++m) y[m] = b1s[m];
    const float* Pn = P + (size_t)n * 32768;
    for (int c = 0; c < 128; ++c) {
        float pv = Pn[c * 256 + t];
        #pragma unroll
        for (int m = 0; m < 8; ++m) y[m] += w1s[m * 128 + c] * pv;
    }
    #pragma unroll
    for (int m = 0; m < 8; ++m) {
        float v = y[m] * s1[m] + t1[m];
        float cl = fminf(fmaxf(v + 3.f, 0.f), 6.f);
        y[m] = v * cl * (1.f / 6.f);
    }
    const float* Ws_ = (t < 128) ? whs : wws;   // wave-uniform
    const float* Bs = (t < 128) ? bhs : bws;
    float* On = A2 + (size_t)n * 32768;
    for (int cc = 0; cc < 32; ++cc) {
        int c = cg * 32 + cc;
        float a = Bs[cc];
        #pragma unroll
        for (int m = 0; m < 8; ++m) a += y[m] * Ws_[cc * 8 + m];
        On[c * 256 + t] = 1.f / (1.f + __expf(-a));
    }
}

// --------------------- attention multiply -> NHWC bf16 (+ fused borders) ---
__device__ __forceinline__ int ldsoff(int w, int c) {
    return w * 128 + ((((c >> 3) ^ ((w & 7) << 1)) << 3) | (c & 7));
}

__global__ __launch_bounds__(256) void amul_kernel(const float* __restrict__ x,
    const float* __restrict__ A2, __hip_bfloat16* __restrict__ Xpad) {
    int nh = blockIdx.x;             // n*128 + h
    int n = nh >> 7, h = nh & 127;
    int t = threadIdx.x;
    __shared__ __align__(16) __hip_bfloat16 T[16384];
    __shared__ float ahs[128];
    if (t < 128) ahs[t] = A2[(size_t)(n * 128 + t) * 256 + h];

    uint4 z = {0u, 0u, 0u, 0u};
    __hip_bfloat16* Xn = Xpad + (size_t)n * 16900 * 128;
    if (t < 32) {
        int wp = (t & 1) ? 129 : 0, cb2 = t >> 1;
        *(uint4*)(Xn + (size_t)((h + 1) * 130 + wp) * 128 + cb2 * 8) = z;
    }
    if (h == 0 || h == 127) {
        int hp = (h == 0) ? 0 : 129;
        for (int i = t; i < 2080; i += 256) {
            int wp = i >> 4, cb2 = i & 15;
            *(uint4*)(Xn + (size_t)(hp * 130 + wp) * 128 + cb2 * 8) = z;
        }
    }
    __syncthreads();

    const float* xr  = x + ((size_t)n * 128 * 128 + h) * 128;
    const float* awr = A2 + (size_t)n * 32768 + 128;
    #pragma unroll
    for (int j = 0; j < 16; ++j) {
        int item = j * 256 + t;
        int c = item >> 5, w4 = item & 31;
        f32x4 xv = *(const f32x4*)(xr + (size_t)c * 16384 + w4 * 4);
        f32x4 av = *(const f32x4*)(awr + c * 256 + w4 * 4);
        float ah = ahs[c];
        #pragma unroll
        for (int k = 0; k < 4; ++k) {
            float val = xv[k] * av[k] * ah;
            T[ldsoff(w4 * 4 + k, c)] = __float2bfloat16(val);
        }
    }
    __syncthreads();
    __hip_bfloat16* orow = Xn + (size_t)((h + 1) * 130 + 1) * 128;
    #pragma unroll
    for (int j = 0; j < 8; ++j) {
        int item = j * 256 + t;
        int w = item >> 4, cb = item & 15;
        int slot = cb ^ ((w & 7) << 1);
        uint4 v = *(const uint4*)&T[w * 128 + slot * 8];
        *(uint4*)(orow + w * 128 + cb * 8) = v;   // linear global layout
    }
}

// ------------------------------------------------------- implicit-GEMM conv -
// 256 threads (4 waves, 2Mx2N), tile M=128(o) x N=128(1 row), BK=32 (36 steps),
// triple-buffered 16KB/buf = 48KB LDS -> 3 blocks/CU (3 anti-phased barrier
// domains), regs <=128/wave. Stage 2-ahead, counted vmcnt(4), one barrier/step.
__global__ __launch_bounds__(256, 4) void conv_kernel(
    const __hip_bfloat16* __restrict__ Xpad, const __hip_bfloat16* __restrict__ Wt,
    const float* __restrict__ ab, float* __restrict__ out) {
    int bid = blockIdx.x;
    int work = (bid & 7) * 128 + (bid >> 3);   // XCD swizzle, 1024 % 8 == 0
    int n = work >> 7, h = work & 127;
    int tid = threadIdx.x;
    int lane = tid & 63, wid = tid >> 6;
    int wm = wid >> 1, wn = wid & 1;
    int r16 = lane & 15, u = lane >> 4;

    __shared__ __align__(16) __hip_bfloat16 Ws[3 * 4096];   // [buf][o=128][k=32]
    __shared__ __align__(16) __hip_bfloat16 Xs[3 * 4096];   // [buf][p=128][k=32]

    const __hip_bfloat16* Xn = Xpad + ((size_t)n * 16900 + (size_t)h * 130) * 128;

    // fragment read offsets (slot involution s = u ^ ((row>>1)&3): 2-way = free)
    int offA[4], offB[4];
    #pragma unroll
    for (int mi = 0; mi < 4; ++mi) {
        int o = wm * 64 + mi * 16 + r16;
        offA[mi] = o * 32 + ((u ^ ((o >> 1) & 3)) << 3);
    }
    #pragma unroll
    for (int ni = 0; ni < 4; ++ni) {
        int p = wn * 64 + ni * 16 + r16;
        offB[ni] = p * 32 + ((u ^ ((p >> 1) & 3)) << 3);
    }

    // X staging: thread -> (pixel p, slot s); source pre-swizzled, LDS dst linear
    int xp[2], xs[2];
    #pragma unroll
    for (int j = 0; j < 2; ++j) {
        int idx = j * 256 + tid;
        xp[j] = idx >> 2;
        xs[j] = (idx & 3) ^ ((xp[j] >> 1) & 3);
    }

    auto stage = [&](int t) {
        int khw = t >> 2, c32 = t & 3;
        int kh = khw / 3, kw = khw - kh * 3;
        #pragma unroll
        for (int j = 0; j < 2; ++j)
            __builtin_amdgcn_global_load_lds(
                (const __attribute__((address_space(1))) void*)(Wt + t * 4096 + (j * 256 + tid) * 8),
                (__attribute__((address_space(3))) void*)(&Ws[(t % 3) * 4096 + (j * 256 + tid) * 8]),
                16, 0, 0);
        const __hip_bfloat16* xsrc = Xn + (size_t)(kh * 130 + kw) * 128 + c32 * 32;
        __hip_bfloat16* xdst = &Xs[(t % 3) * 4096];
        #pragma unroll
        for (int j = 0; j < 2; ++j)
            __builtin_amdgcn_global_load_lds(
                (const __attribute__((address_space(1))) void*)(xsrc + xp[j] * 128 + xs[j] * 8),
                (__attribute__((address_space(3))) void*)(xdst + (j * 256 + tid) * 8),
                16, 0, 0);
    };

    f32x4 acc[4][4];
    #pragma unroll
    for (int i = 0; i < 4; ++i)
        #pragma unroll
        for (int j = 0; j < 4; ++j) acc[i][j] = (f32x4){0.f, 0.f, 0.f, 0.f};

    // prologue: stage steps 0,1 (8 vm-ops/thread); wait for step 0's 4
    stage(0);
    stage(1);
    asm volatile("s_waitcnt vmcnt(4)" ::: "memory");
    __builtin_amdgcn_sched_barrier(0);
    __builtin_amdgcn_s_barrier();
    __builtin_amdgcn_sched_barrier(0);

    #pragma unroll
    for (int t = 0; t < 36; ++t) {
        const __hip_bfloat16* Wb = &Ws[(t % 3) * 4096];
        const __hip_bfloat16* Xr = &Xs[(t % 3) * 4096];
        if (t + 2 < 36) stage(t + 2);

        bf16x8 fa[4], fb[4];
        #pragma unroll
        for (int mi = 0; mi < 4; ++mi) fa[mi] = *(const bf16x8*)&Wb[offA[mi]];
        #pragma unroll
        for (int ni = 0; ni < 4; ++ni) fb[ni] = *(const bf16x8*)&Xr[offB[ni]];
        asm volatile("s_waitcnt lgkmcnt(0)" ::: "memory");
        __builtin_amdgcn_sched_barrier(0);
        __builtin_amdgcn_s_setprio(1);
        #pragma unroll
        for (int mi = 0; mi < 4; ++mi)
            #pragma unroll
            for (int ni = 0; ni < 4; ++ni)
                acc[mi][ni] = __builtin_amdgcn_mfma_f32_16x16x32_bf16(
                    fa[mi], fb[ni], acc[mi][ni], 0, 0, 0);
        __builtin_amdgcn_s_setprio(0);

        // counted boundary: stage(t+1) complete, stage(t+2)'s 4 stay in flight
        if (t < 34) {
            asm volatile("s_waitcnt vmcnt(4)" ::: "memory");
        } else if (t == 34) {
            asm volatile("s_waitcnt vmcnt(0)" ::: "memory");
        }
        __builtin_amdgcn_sched_barrier(0);
        if (t < 35) {
            __builtin_amdgcn_s_barrier();
            __builtin_amdgcn_sched_barrier(0);
        }
    }

    // fused bias + BN + SiLU epilogue
    #pragma unroll
    for (int mi = 0; mi < 4; ++mi) {
        #pragma unroll
        for (int r = 0; r < 4; ++r) {
            int o = wm * 64 + mi * 16 + u * 4 + r;
            float al = ab[o], be = ab[128 + o];
            size_t obase = (((size_t)n * 128 + o) * 128 + h) * 128;
            #pragma unroll
            for (int ni = 0; ni < 4; ++ni) {
                int p = wn * 64 + ni * 16 + r16;
                float z = acc[mi][ni][r] * al + be;
                out[obase + p] = z / (1.f + __expf(-z));
            }
        }
    }
}

// ----------------------------------------------------------------- launch ---
extern "C" void kernel_launch(void* const* d_in, const int* in_sizes, int n_in,
                              void* d_out, int out_size, void* d_ws, size_t ws_size,
                              hipStream_t stream) {
    const float* x   = (const float*)d_in[0];
    const float* w1  = (const float*)d_in[1];
    const float* b1  = (const float*)d_in[2];
    const float* g1  = (const float*)d_in[3];
    const float* be1 = (const float*)d_in[4];
    const float* m1  = (const float*)d_in[5];
    const float* v1  = (const float*)d_in[6];
    const float* wh  = (const float*)d_in[7];
    const float* bh  = (const float*)d_in[8];
    const float* ww  = (const float*)d_in[9];
    const float* bw  = (const float*)d_in[10];
    const float* wc  = (const float*)d_in[11];
    const float* bc  = (const float*)d_in[12];
    const float* g2  = (const float*)d_in[13];
    const float* be2 = (const float*)d_in[14];
    const float* m2  = (const float*)d_in[15];
    const float* v2  = (const float*)d_in[16];
    float* out = (float*)d_out;

    char* ws = (char*)d_ws;
    float* P  = (float*)(ws);                                   // 1 MiB
    float* A2 = (float*)(ws + (1 << 20));                       // 1 MiB
    __hip_bfloat16* Xpad = (__hip_bfloat16*)(ws + (2 << 20));   // 34,611,200 B
    __hip_bfloat16* Wt   = (__hip_bfloat16*)(ws + (2 << 20) + 34611200);  // 294,912 B
    float* ab = (float*)(ws + (2 << 20) + 34611200 + 294912);   // 1 KiB

    pool_kernel<<<1024, 256, 0, stream>>>(x, P);
    attn_wtrans_kernel<<<608, 256, 0, stream>>>(P, w1, b1, g1, be1, m1, v1,
                                                wh, bh, ww, bw, wc, bc, g2, be2, m2, v2,
                                                A2, Wt, ab);
    amul_kernel<<<1024, 256, 0, stream>>>(x, A2, Xpad);
    conv_kernel<<<1024, 256, 0, stream>>>(Xpad, Wt, ab, out);
}

// Round 10
// 108.084 us; speedup vs baseline: 1.0550x; 1.0550x over previous
//
#include <hip/hip_runtime.h>
#include <hip/hip_bf16.h>

typedef float f32x4 __attribute__((ext_vector_type(4)));
typedef __bf16 bf16x8 __attribute__((ext_vector_type(8)));

#define EPSF 1e-5f

// ---------------------------------------------------------------- pooling ---
__device__ __forceinline__ float pw(int i) {
    return (1.0f + (i < 64 ? 2.0f : 0.0f) + (i < 32 ? 4.0f : 0.0f)) * (1.0f / 128.0f);
}

__global__ __launch_bounds__(256) void pool_kernel(const float* __restrict__ x,
                                                   float* __restrict__ P) {
    int nc = blockIdx.x;  // n*128 + c
    const f32x4* plane = (const f32x4*)(x + (size_t)nc * 16384);
    __shared__ float rowpart[128][33];
    __shared__ __align__(16) f32x4 colpart[8][32];
    int t = threadIdx.x;
    int wq = t & 31, hg = t >> 5;
    f32x4 cacc = {0.f, 0.f, 0.f, 0.f};
    float u0 = pw(wq * 4), u1 = pw(wq * 4 + 1), u2 = pw(wq * 4 + 2), u3 = pw(wq * 4 + 3);
    #pragma unroll
    for (int j = 0; j < 16; ++j) {
        int r = hg * 16 + j;
        f32x4 v = plane[r * 32 + wq];
        rowpart[r][wq] = v.x * u0 + v.y * u1 + v.z * u2 + v.w * u3;
        cacc += v * pw(r);
    }
    colpart[hg][wq] = cacc;
    __syncthreads();
    float s = 0.f;
    if (t < 128) {
        #pragma unroll
        for (int q = 0; q < 32; ++q) s += rowpart[t][q];
        P[(size_t)nc * 256 + t] = s;
    } else {
        int w = t - 128;
        const float* cp = (const float*)colpart;
        #pragma unroll
        for (int g = 0; g < 8; ++g) s += cp[g * 128 + w];
        P[(size_t)nc * 256 + 128 + w] = s;
    }
}

// ------------------------- attention vectors + fused weight transform -------
__global__ __launch_bounds__(256) void attn_wtrans_kernel(const float* __restrict__ P,
    const float* __restrict__ w1, const float* __restrict__ b1,
    const float* __restrict__ g1, const float* __restrict__ be1,
    const float* __restrict__ m1, const float* __restrict__ v1,
    const float* __restrict__ wh, const float* __restrict__ bh,
    const float* __restrict__ ww, const float* __restrict__ bw,
    const float* __restrict__ wc, const float* __restrict__ bc,
    const float* __restrict__ g2, const float* __restrict__ be2,
    const float* __restrict__ m2, const float* __restrict__ v2,
    float* __restrict__ A2, __hip_bfloat16* __restrict__ Wt, float* __restrict__ ab) {
    int t = threadIdx.x;
    if (blockIdx.x >= 32) {
        int g = (blockIdx.x - 32) * 256 + t;   // 576*256 == 147456
        int step = g >> 12, rem = g & 4095;
        int o = rem >> 5, m = rem & 31;
        int slotp = m >> 3, j = m & 7;
        int u = slotp ^ ((o >> 1) & 3);
        int kidx = u * 8 + j;
        int khw = step >> 2, c32 = step & 3;
        int c = c32 * 32 + kidx;
        Wt[g] = __float2bfloat16(wc[(o * 128 + c) * 9 + khw]);
        if (g < 128) {
            float s2 = g2[g] * rsqrtf(v2[g] + EPSF);
            ab[g] = s2;
            ab[128 + g] = bc[g] * s2 + be2[g] - m2[g] * s2;
        }
        return;
    }
    int n = blockIdx.x >> 2, cg = blockIdx.x & 3;
    __shared__ float w1s[1024], whs[256], wws[256];
    __shared__ float bhs[32], bws[32];
    __shared__ float s1[8], t1[8], b1s[8];
    for (int i = t; i < 1024; i += 256) w1s[i] = w1[i];
    whs[t] = wh[cg * 256 + t];
    wws[t] = ww[cg * 256 + t];
    if (t < 32) { bhs[t] = bh[cg * 32 + t]; bws[t] = bw[cg * 32 + t]; }
    if (t < 8) {
        float s = g1[t] * rsqrtf(v1[t] + EPSF);
        s1[t] = s; t1[t] = be1[t] - m1[t] * s; b1s[t] = b1[t];
    }
    __syncthreads();
    float y[8];
    #pragma unroll
    for (int m = 0; m < 8; ++m) y[m] = b1s[m];
    const float* Pn = P + (size_t)n * 32768;
    for (int c = 0; c < 128; ++c) {
        float pv = Pn[c * 256 + t];
        #pragma unroll
        for (int m = 0; m < 8; ++m) y[m] += w1s[m * 128 + c] * pv;
    }
    #pragma unroll
    for (int m = 0; m < 8; ++m) {
        float v = y[m] * s1[m] + t1[m];
        float cl = fminf(fmaxf(v + 3.f, 0.f), 6.f);
        y[m] = v * cl * (1.f / 6.f);
    }
    const float* Ws_ = (t < 128) ? whs : wws;   // wave-uniform
    const float* Bs = (t < 128) ? bhs : bws;
    float* On = A2 + (size_t)n * 32768;
    for (int cc = 0; cc < 32; ++cc) {
        int c = cg * 32 + cc;
        float a = Bs[cc];
        #pragma unroll
        for (int m = 0; m < 8; ++m) a += y[m] * Ws_[cc * 8 + m];
        On[c * 256 + t] = 1.f / (1.f + __expf(-a));
    }
}

// --------------------- attention multiply -> NHWC bf16 (+ fused borders) ---
__device__ __forceinline__ int ldsoff(int w, int c) {
    return w * 128 + ((((c >> 3) ^ ((w & 7) << 1)) << 3) | (c & 7));
}

__global__ __launch_bounds__(256) void amul_kernel(const float* __restrict__ x,
    const float* __restrict__ A2, __hip_bfloat16* __restrict__ Xpad) {
    int nh = blockIdx.x;             // n*128 + h
    int n = nh >> 7, h = nh & 127;
    int t = threadIdx.x;
    __shared__ __align__(16) __hip_bfloat16 T[16384];
    __shared__ float ahs[128];
    if (t < 128) ahs[t] = A2[(size_t)(n * 128 + t) * 256 + h];

    uint4 z = {0u, 0u, 0u, 0u};
    __hip_bfloat16* Xn = Xpad + (size_t)n * 16900 * 128;
    if (t < 32) {
        int wp = (t & 1) ? 129 : 0, cb2 = t >> 1;
        *(uint4*)(Xn + (size_t)((h + 1) * 130 + wp) * 128 + cb2 * 8) = z;
    }
    if (h == 0 || h == 127) {
        int hp = (h == 0) ? 0 : 129;
        for (int i = t; i < 2080; i += 256) {
            int wp = i >> 4, cb2 = i & 15;
            *(uint4*)(Xn + (size_t)(hp * 130 + wp) * 128 + cb2 * 8) = z;
        }
    }
    __syncthreads();

    const float* xr  = x + ((size_t)n * 128 * 128 + h) * 128;
    const float* awr = A2 + (size_t)n * 32768 + 128;
    #pragma unroll
    for (int j = 0; j < 16; ++j) {
        int item = j * 256 + t;
        int c = item >> 5, w4 = item & 31;
        f32x4 xv = *(const f32x4*)(xr + (size_t)c * 16384 + w4 * 4);
        f32x4 av = *(const f32x4*)(awr + c * 256 + w4 * 4);
        float ah = ahs[c];
        #pragma unroll
        for (int k = 0; k < 4; ++k) {
            float val = xv[k] * av[k] * ah;
            T[ldsoff(w4 * 4 + k, c)] = __float2bfloat16(val);
        }
    }
    __syncthreads();
    __hip_bfloat16* orow = Xn + (size_t)((h + 1) * 130 + 1) * 128;
    #pragma unroll
    for (int j = 0; j < 8; ++j) {
        int item = j * 256 + t;
        int w = item >> 4, cb = item & 15;
        int slot = cb ^ ((w & 7) << 1);
        uint4 v = *(const uint4*)&T[w * 128 + slot * 8];
        *(uint4*)(orow + w * 128 + cb * 8) = v;   // linear global layout
    }
}

// ------------------------------------------------------- implicit-GEMM conv -
// R5 geometry: 512 threads (8 waves, 2Mx4N), tile M=128(o) x N=256(2 rows),
// BK=32 (36 steps), triple-buffered 24KB/buf = 72KB LDS (2 blocks/CU).
// Stage 2-ahead, counted vmcnt(3), ONE barrier/step. ds_read->MFMA region is
// UNPINNED: compiler emits per-operand counted lgkmcnt so reads overlap MFMA.
__global__ __launch_bounds__(512, 4) void conv_kernel(
    const __hip_bfloat16* __restrict__ Xpad, const __hip_bfloat16* __restrict__ Wt,
    const float* __restrict__ ab, float* __restrict__ out) {
    int bid = blockIdx.x;
    int work = (bid & 7) * 64 + (bid >> 3);   // XCD swizzle, 512 % 8 == 0
    int n = work >> 6, h0 = (work & 63) * 2;
    int tid = threadIdx.x;
    int lane = tid & 63, wid = tid >> 6;
    int wm = wid >> 2, wn = wid & 3;
    int r16 = lane & 15, u = lane >> 4;

    __shared__ __align__(16) __hip_bfloat16 Ws[3 * 4096];   // [buf][o=128][k=32]
    __shared__ __align__(16) __hip_bfloat16 Xs[3 * 8192];   // [buf][p=256][k=32]

    const __hip_bfloat16* Xn = Xpad + ((size_t)n * 16900 + (size_t)h0 * 130) * 128;

    // fragment read offsets (slot involution s = u ^ ((row>>1)&3): 2-way = free)
    int offA[4], offB[4];
    #pragma unroll
    for (int mi = 0; mi < 4; ++mi) {
        int o = wm * 64 + mi * 16 + r16;
        offA[mi] = o * 32 + ((u ^ ((o >> 1) & 3)) << 3);
    }
    #pragma unroll
    for (int ni = 0; ni < 4; ++ni) {
        int p = wn * 64 + ni * 16 + r16;
        offB[ni] = p * 32 + ((u ^ ((p >> 1) & 3)) << 3);
    }

    // X staging source offsets (pre-swizzled global side; LDS dst linear)
    int xo[2];
    #pragma unroll
    for (int j = 0; j < 2; ++j) {
        int idx = j * 512 + tid, p = idx >> 2, s = idx & 3;
        int r2 = p >> 7, w = p & 127;
        xo[j] = (r2 * 130 + w) * 128 + ((s ^ ((p >> 1) & 3)) << 3);
    }

    auto stage = [&](int t) {
        int khw = t >> 2, c32 = t & 3;
        int kh = khw / 3, kw = khw - kh * 3;
        __builtin_amdgcn_global_load_lds(
            (const __attribute__((address_space(1))) void*)(Wt + t * 4096 + tid * 8),
            (__attribute__((address_space(3))) void*)(&Ws[(t % 3) * 4096 + tid * 8]),
            16, 0, 0);
        const __hip_bfloat16* xsrc = Xn + (kh * 130 + kw) * 128 + c32 * 32;
        __hip_bfloat16* xdst = &Xs[(t % 3) * 8192];
        #pragma unroll
        for (int j = 0; j < 2; ++j)
            __builtin_amdgcn_global_load_lds(
                (const __attribute__((address_space(1))) void*)(xsrc + xo[j]),
                (__attribute__((address_space(3))) void*)(xdst + (j * 512 + tid) * 8),
                16, 0, 0);
    };

    f32x4 acc[4][4];
    #pragma unroll
    for (int i = 0; i < 4; ++i)
        #pragma unroll
        for (int j = 0; j < 4; ++j) acc[i][j] = (f32x4){0.f, 0.f, 0.f, 0.f};

    // prologue: stage steps 0,1 (6 loads/thread); wait for step 0's 3
    stage(0);
    stage(1);
    asm volatile("s_waitcnt vmcnt(3)" ::: "memory");
    __builtin_amdgcn_sched_barrier(0);
    __builtin_amdgcn_s_barrier();
    __builtin_amdgcn_sched_barrier(0);

    #pragma unroll
    for (int t = 0; t < 36; ++t) {
        const __hip_bfloat16* Wb = &Ws[(t % 3) * 4096];
        const __hip_bfloat16* Xr = &Xs[(t % 3) * 8192];
        if (t + 2 < 36) stage(t + 2);

        // UNPINNED reads + MFMA: compiler schedules counted lgkmcnt per operand
        bf16x8 fa[4], fb[4];
        #pragma unroll
        for (int mi = 0; mi < 4; ++mi) fa[mi] = *(const bf16x8*)&Wb[offA[mi]];
        #pragma unroll
        for (int ni = 0; ni < 4; ++ni) fb[ni] = *(const bf16x8*)&Xr[offB[ni]];
        #pragma unroll
        for (int mi = 0; mi < 4; ++mi)
            #pragma unroll
            for (int ni = 0; ni < 4; ++ni)
                acc[mi][ni] = __builtin_amdgcn_mfma_f32_16x16x32_bf16(
                    fa[mi], fb[ni], acc[mi][ni], 0, 0, 0);

        // step boundary: counted vmcnt (stage(t+1) landed; t+2's 3 in flight)
        if (t < 34) {
            asm volatile("s_waitcnt vmcnt(3)" ::: "memory");
        } else if (t == 34) {
            asm volatile("s_waitcnt vmcnt(0)" ::: "memory");
        }
        __builtin_amdgcn_sched_barrier(0);
        if (t < 35) {
            __builtin_amdgcn_s_barrier();
            __builtin_amdgcn_sched_barrier(0);
        }
    }

    // fused bias + BN + SiLU epilogue
    #pragma unroll
    for (int mi = 0; mi < 4; ++mi) {
        #pragma unroll
        for (int r = 0; r < 4; ++r) {
            int o = wm * 64 + mi * 16 + u * 4 + r;
            float al = ab[o], be = ab[128 + o];
            size_t obase = (((size_t)n * 128 + o) * 128 + h0) * 128;
            #pragma unroll
            for (int ni = 0; ni < 4; ++ni) {
                int p = wn * 64 + ni * 16 + r16;
                int r2 = p >> 7, w = p & 127;
                float z = acc[mi][ni][r] * al + be;
                out[obase + r2 * 128 + w] = z / (1.f + __expf(-z));
            }
        }
    }
}

// ----------------------------------------------------------------- launch ---
extern "C" void kernel_launch(void* const* d_in, const int* in_sizes, int n_in,
                              void* d_out, int out_size, void* d_ws, size_t ws_size,
                              hipStream_t stream) {
    const float* x   = (const float*)d_in[0];
    const float* w1  = (const float*)d_in[1];
    const float* b1  = (const float*)d_in[2];
    const float* g1  = (const float*)d_in[3];
    const float* be1 = (const float*)d_in[4];
    const float* m1  = (const float*)d_in[5];
    const float* v1  = (const float*)d_in[6];
    const float* wh  = (const float*)d_in[7];
    const float* bh  = (const float*)d_in[8];
    const float* ww  = (const float*)d_in[9];
    const float* bw  = (const float*)d_in[10];
    const float* wc  = (const float*)d_in[11];
    const float* bc  = (const float*)d_in[12];
    const float* g2  = (const float*)d_in[13];
    const float* be2 = (const float*)d_in[14];
    const float* m2  = (const float*)d_in[15];
    const float* v2  = (const float*)d_in[16];
    float* out = (float*)d_out;

    char* ws = (char*)d_ws;
    float* P  = (float*)(ws);                                   // 1 MiB
    float* A2 = (float*)(ws + (1 << 20));                       // 1 MiB
    __hip_bfloat16* Xpad = (__hip_bfloat16*)(ws + (2 << 20));   // 34,611,200 B
    __hip_bfloat16* Wt   = (__hip_bfloat16*)(ws + (2 << 20) + 34611200);  // 294,912 B
    float* ab = (float*)(ws + (2 << 20) + 34611200 + 294912);   // 1 KiB

    pool_kernel<<<1024, 256, 0, stream>>>(x, P);
    attn_wtrans_kernel<<<608, 256, 0, stream>>>(P, w1, b1, g1, be1, m1, v1,
                                                wh, bh, ww, bw, wc, bc, g2, be2, m2, v2,
                                                A2, Wt, ab);
    amul_kernel<<<1024, 256, 0, stream>>>(x, A2, Xpad);
    conv_kernel<<<512, 512, 0, stream>>>(Xpad, Wt, ab, out);
}